// Round 8
// baseline (156.204 us; speedup 1.0000x reference)
//
#include <hip/hip_runtime.h>

// EnhancedMoEModel: B=524288, D=32, H=64, H2=32, E=8, O=1. fp32 in/out.
// out[b] = sum_e sigmoid(relu(relu(x W1e + b1e) W2e + b2e) W3e + b3e) * probs[b,e]
//
// R17: LDS-port decongestion. R13b and R16 both plateau at 48.5us despite
// opposite occupancy/ILP configs -> shared-resource bound: ~128 ds_read_b128
// per wave x 16384 waves = 8192 ops/CU x ~12cyc = ~41us of LDS port time.
// Changes:
//  - 4 row-tiles per wave (64 rows): per-expert weight/bias reads amortize
//    over 2x MFMAs; waves halve. ILP = 4 row-tile chains per stage
//    (2-expert pair interleave dropped).
//  - biases/W3/b3 read from the prebuilt global img (L1-hot broadcast, VMEM
//    pipe) instead of LDS -> LDS holds only the 64KB weight section,
//    8 LDS ops/expert. LDS load ~10us/CU, under the 18.6us MFMA floor.
//
// Fragment math (verified R8/R10 end-to-end, dtype-independent C/D layout):
// 16x16x32 MFMA with A[m=lane&15][k=8q+j], B[k=8q+j][n=lane&15],
// D[m=4q+r][n]: per-lane reg r. Hidden-unit column permutation
// hmap(mt,n)=32(mt>>1)+8(n>>2)+4(mt&1)+(n&3) makes layer-N output registers
// exactly the next layer's B-fragment.
//
// ws image layout (byte offsets):
//   [0,      65536): weight frags, 16B each, F = addr/16:
//       w1: F = e*256 + 64*mt + 16*q + n
//       w2: F = 2048 + e*256 + 128*kb2 + 64*mt2 + 16*q + n
//   [65536, 67584): b1 frags  f32x4, idx = e*16 + mt*4 + q
//   [67584, 68608): b2 frags  f32x4, idx = e*8 + mt2*4 + q
//   [68608, 69120): a3 frags  f16x8, idx = e*4 + q
//   [69120, 69152): b3[0..7] f32

typedef __attribute__((ext_vector_type(8))) _Float16 f16x8;
typedef __attribute__((ext_vector_type(2))) __fp16 h16x2;
typedef __attribute__((ext_vector_type(4))) float f32x4;

__device__ __forceinline__ unsigned pkh(float lo, float hi) {
    union { h16x2 v; unsigned u; } t;
    t.v = __builtin_amdgcn_cvt_pkrtz(lo, hi);
    return t.u;
}

// packed relu on 2 x f16 (relu-after-pack == relu-before-pack for RTZ)
__device__ __forceinline__ unsigned relu2(unsigned a) {
    unsigned r;
    asm("v_pk_max_f16 %0, %1, 0" : "=v"(r) : "v"(a));
    return r;
}

__device__ __forceinline__ float sigf(float s) {
    return 1.f / (1.f + __expf(-s));
}

#define MFMA32(a, b, c) __builtin_amdgcn_mfma_f32_16x16x32_f16((a), (b), (c), 0, 0, 0)

__global__ __launch_bounds__(1024)
void build_image(const float* __restrict__ W1, const float* __restrict__ b1,
                 const float* __restrict__ W2, const float* __restrict__ b2,
                 const float* __restrict__ W3, const float* __restrict__ b3,
                 char* __restrict__ ws) {
    const int tid = threadIdx.x;
    #pragma unroll
    for (int k = 0; k < 4; ++k) {
        const int F = tid + k * 1024;
        const int e = (F >> 8) & 7, s = F & 255;
        const int qq = (s >> 4) & 3, nn = s & 15;
        const float* src;
        int stride;
        if (F < 2048) {          // W1[e][d=8qq+j][hmap(mt,nn)], j strides d
            const int mt = s >> 6;
            const int h = 32 * (mt >> 1) + 8 * (nn >> 2) + 4 * (mt & 1) + (nn & 3);
            src = W1 + (e * 32 + 8 * qq) * 64 + h;
            stride = 64;
        } else {                 // W2[e][h=32kb2+8qq+j][h2map(mt2,nn)], j strides h
            const int kb2 = (s >> 7) & 1, mt2 = (s >> 6) & 1;
            const int h2 = 8 * (nn >> 2) + 4 * mt2 + (nn & 3);
            src = W2 + (e * 64 + 32 * kb2 + 8 * qq) * 32 + h2;
            stride = 32;
        }
        union { f16x8 v; unsigned u[4]; } t;
        t.u[0] = pkh(src[0 * stride], src[1 * stride]);
        t.u[1] = pkh(src[2 * stride], src[3 * stride]);
        t.u[2] = pkh(src[4 * stride], src[5 * stride]);
        t.u[3] = pkh(src[6 * stride], src[7 * stride]);
        *(f16x8*)(ws + F * 16) = t.v;
    }
    if (tid < 128) {                       // b1 frags
        const int e = tid >> 4, mt = (tid >> 2) & 3, q = tid & 3;
        *(f32x4*)(ws + 65536 + tid * 16) =
            *(const f32x4*)(b1 + e * 64 + 32 * (mt >> 1) + 4 * (mt & 1) + 8 * q);
    } else if (tid < 192) {                // b2 frags
        const int i = tid - 128, e = i >> 3, mt2 = (i >> 2) & 1, q = i & 3;
        *(f32x4*)(ws + 67584 + i * 16) =
            *(const f32x4*)(b2 + e * 32 + 4 * mt2 + 8 * q);
    } else if (tid < 224) {                // a3 frags (pre-packed f16)
        const int i = tid - 192, e = i >> 2, q = i & 3;
        const f32x4 lo = *(const f32x4*)(W3 + e * 32 + 8 * q);
        const f32x4 hi = *(const f32x4*)(W3 + e * 32 + 8 * q + 4);
        union { f16x8 v; unsigned u[4]; } a;
        a.u[0] = pkh(lo.x, lo.y); a.u[1] = pkh(lo.z, lo.w);
        a.u[2] = pkh(hi.x, hi.y); a.u[3] = pkh(hi.z, hi.w);
        *(f16x8*)(ws + 68608 + i * 16) = a.v;
    } else if (tid < 232) {                // b3
        const int i = tid - 224;
        *(float*)(ws + 69120 + i * 4) = b3[i];
    }
}

__global__ __launch_bounds__(512, 4)
void moe_fused(const float* __restrict__ x, const float* __restrict__ probs,
               const char* __restrict__ img, float* __restrict__ out) {
    __shared__ __attribute__((aligned(16))) char ldsraw[65536];   // weights only
    const int tid = threadIdx.x;
    const int w = tid >> 6, lane = tid & 63, n = lane & 15, q = lane >> 4;

    // ---- prologue: linear coalesced copy of the weight section.
    #pragma unroll
    for (int k = 0; k < 8; ++k) {
        const int off = tid * 16 + k * 8192;
        *(f32x4*)(ldsraw + off) = *(const f32x4*)(img + off);
    }

    // ---- per-wave x tiles: wave owns rows rb..rb+63 (four 16-row tiles).
    const int rb = blockIdx.x * 512 + w * 64;
    union { f16x8 v; unsigned u[4]; } xf[4];
    #pragma unroll
    for (int rt = 0; rt < 4; ++rt) {
        const float* xp = x + (size_t)(rb + rt * 16 + n) * 32 + q * 8;
        const f32x4 xa = *(const f32x4*)xp, xb = *(const f32x4*)(xp + 4);
        xf[rt].u[0] = pkh(xa.x, xa.y); xf[rt].u[1] = pkh(xa.z, xa.w);
        xf[rt].u[2] = pkh(xb.x, xb.y); xf[rt].u[3] = pkh(xb.z, xb.w);
    }

    __syncthreads();

    const short* wl = (const short*)ldsraw + (n * 8 + q * 128);
    const char* gb1 = img + 65536 + q * 16;   // + e*256 + mt*64   (global, L1-hot)
    const char* gb2 = img + 67584 + q * 16;   // + e*128 + mt2*64
    const char* ga3 = img + 68608 + q * 16;   // + e*64
    const float* gb3 = (const float*)(img + 69120);
    const float* pba = probs + (size_t)(rb + n) * 8;   // + e + rt*128
    float r[4] = {0.f, 0.f, 0.f, 0.f};

    #pragma unroll 1
    for (int e = 0; e < 8; ++e) {
        const short* we = wl + e * 2048;

        // Layer 1: 4 mt-tiles x 4 row-tiles. pack+relu into P[rt][kb2]
        // (element j <-> h = 32kb2 + 8q + j).
        union { f16x8 v; unsigned u[4]; } P[4][2];
        #pragma unroll
        for (int mt = 0; mt < 4; ++mt) {
            const f16x8 w1f = *(const f16x8*)(we + mt * 512);
            const f32x4 bf = *(const f32x4*)(gb1 + e * 256 + mt * 64);
            f32x4 c[4];
            #pragma unroll
            for (int rt = 0; rt < 4; ++rt) c[rt] = MFMA32(w1f, xf[rt].v, bf);
            #pragma unroll
            for (int rt = 0; rt < 4; ++rt) {
                P[rt][mt >> 1].u[(mt & 1) * 2 + 0] = relu2(pkh(c[rt].x, c[rt].y));
                P[rt][mt >> 1].u[(mt & 1) * 2 + 1] = relu2(pkh(c[rt].z, c[rt].w));
            }
        }

        // Layer 2: 2 mt2 x 2 kb2 x 4 row-tiles. pack+relu into PC[rt]
        // (element j <-> h2 = 8q+j).
        union { f16x8 v; unsigned u[4]; } PC[4];
        #pragma unroll
        for (int mt2 = 0; mt2 < 2; ++mt2) {
            const f32x4 bf = *(const f32x4*)(gb2 + e * 128 + mt2 * 64);
            f32x4 c[4];
            #pragma unroll
            for (int rt = 0; rt < 4; ++rt) c[rt] = bf;
            #pragma unroll
            for (int kb2 = 0; kb2 < 2; ++kb2) {
                const f16x8 w2f =
                    *(const f16x8*)(we + 16384 + mt2 * 512 + kb2 * 1024);
                #pragma unroll
                for (int rt = 0; rt < 4; ++rt)
                    c[rt] = MFMA32(w2f, P[rt][kb2].v, c[rt]);
            }
            #pragma unroll
            for (int rt = 0; rt < 4; ++rt) {
                PC[rt].u[mt2 * 2 + 0] = relu2(pkh(c[rt].x, c[rt].y));
                PC[rt].u[mt2 * 2 + 1] = relu2(pkh(c[rt].z, c[rt].w));
            }
        }

        // Layer 3: pre-packed w3 frag (global); b3 seeded into C operand.
        const f16x8 a3v = *(const f16x8*)(ga3 + e * 64);
        const float bb = gb3[e];   // wave-uniform -> scalar load
        const f32x4 cb = {bb, bb, bb, bb};
        #pragma unroll
        for (int rt = 0; rt < 4; ++rt) {
            const f32x4 s = MFMA32(a3v, PC[rt].v, cb);
            r[rt] = fmaf(sigf(s.x), pba[e + rt * 128], r[rt]);
        }
    }

    if (q == 0) {
        #pragma unroll
        for (int rt = 0; rt < 4; ++rt) out[rb + rt * 16 + n] = r[rt];
    }
}

extern "C" void kernel_launch(void* const* d_in, const int* in_sizes, int n_in,
                              void* d_out, int out_size, void* d_ws, size_t ws_size,
                              hipStream_t stream) {
    const float* x     = (const float*)d_in[0];
    const float* probs = (const float*)d_in[1];
    const float* W1    = (const float*)d_in[2];
    const float* b1    = (const float*)d_in[3];
    const float* W2    = (const float*)d_in[4];
    const float* b2    = (const float*)d_in[5];
    const float* W3    = (const float*)d_in[6];
    const float* b3    = (const float*)d_in[7];

    hipLaunchKernelGGL(build_image, dim3(1), dim3(1024), 0, stream,
                       W1, b1, W2, b2, W3, b3, (char*)d_ws);
    const int nrows = in_sizes[0] / 32;          // 524288
    hipLaunchKernelGGL(moe_fused, dim3(nrows / 512), dim3(512), 0, stream,
                       x, probs, (const char*)d_ws, (float*)d_out);
}

// Round 10
// 145.746 us; speedup vs baseline: 1.0717x; 1.0717x over previous
//
#include <hip/hip_runtime.h>

// EnhancedMoEModel: B=524288, D=32, H=64, H2=32, E=8, O=1. fp32 in/out.
// out[b] = sum_e sigmoid(relu(relu(x W1e + b1e) W2e + b2e) W3e + b3e) * probs[b,e]
//
// R18 (resubmit; R9 was an infra failure): R17's 4-row-tile wave (32
// waves/CU, halved per-CU weight LDS traffic) + R16's biases-in-LDS (no
// in-loop global VMEM on the C-operand chain -- R17's regression source).
// Theory: 48.5us plateau (R13b/R16) was LDS-port-bound at 64 waves/CU x
// ~120 LDS insts/wave ~= 40us; R17 fixed LDS but serialized on global
// bias latency at VGPR=64. This version: LDS ~64 weight-reads + ~57
// broadcast bias-reads per wave at 32 waves/CU ~= 11-19us, under the
// 15-19us MFMA floor -> MFMA-bound.
//
// Fragment math (verified R8/R10 end-to-end, dtype-independent C/D layout):
// 16x16x32 MFMA with A[m=lane&15][k=8q+j], B[k=8q+j][n=lane&15],
// D[m=4q+r][n]: per-lane reg r. Hidden-unit column permutation
// hmap(mt,n)=32(mt>>1)+8(n>>2)+4(mt&1)+(n&3) makes layer-N output registers
// exactly the next layer's B-fragment.
//
// LDS/ws image layout (byte offsets):
//   [0,      65536): weight frags, 16B each, F = addr/16:
//       w1: F = e*256 + 64*mt + 16*q + n
//       w2: F = 2048 + e*256 + 128*kb2 + 64*mt2 + 16*q + n
//   [65536, 67584): b1 frags  f32x4, idx = e*16 + mt*4 + q
//   [67584, 68608): b2 frags  f32x4, idx = e*8 + mt2*4 + q
//   [68608, 69120): a3 frags  f16x8, idx = e*4 + q
//   [69120, 69152): b3[0..7] f32

typedef __attribute__((ext_vector_type(8))) _Float16 f16x8;
typedef __attribute__((ext_vector_type(2))) __fp16 h16x2;
typedef __attribute__((ext_vector_type(4))) float f32x4;

__device__ __forceinline__ unsigned pkh(float lo, float hi) {
    union { h16x2 v; unsigned u; } t;
    t.v = __builtin_amdgcn_cvt_pkrtz(lo, hi);
    return t.u;
}

// packed relu on 2 x f16 (relu-after-pack == relu-before-pack for RTZ)
__device__ __forceinline__ unsigned relu2(unsigned a) {
    unsigned r;
    asm("v_pk_max_f16 %0, %1, 0" : "=v"(r) : "v"(a));
    return r;
}

__device__ __forceinline__ float sigf(float s) {
    return 1.f / (1.f + __expf(-s));
}

#define MFMA32(a, b, c) __builtin_amdgcn_mfma_f32_16x16x32_f16((a), (b), (c), 0, 0, 0)

__global__ __launch_bounds__(1024)
void build_image(const float* __restrict__ W1, const float* __restrict__ b1,
                 const float* __restrict__ W2, const float* __restrict__ b2,
                 const float* __restrict__ W3, const float* __restrict__ b3,
                 char* __restrict__ ws) {
    const int tid = threadIdx.x;
    #pragma unroll
    for (int k = 0; k < 4; ++k) {
        const int F = tid + k * 1024;
        const int e = (F >> 8) & 7, s = F & 255;
        const int qq = (s >> 4) & 3, nn = s & 15;
        const float* src;
        int stride;
        if (F < 2048) {          // W1[e][d=8qq+j][hmap(mt,nn)], j strides d
            const int mt = s >> 6;
            const int h = 32 * (mt >> 1) + 8 * (nn >> 2) + 4 * (mt & 1) + (nn & 3);
            src = W1 + (e * 32 + 8 * qq) * 64 + h;
            stride = 64;
        } else {                 // W2[e][h=32kb2+8qq+j][h2map(mt2,nn)], j strides h
            const int kb2 = (s >> 7) & 1, mt2 = (s >> 6) & 1;
            const int h2 = 8 * (nn >> 2) + 4 * mt2 + (nn & 3);
            src = W2 + (e * 64 + 32 * kb2 + 8 * qq) * 32 + h2;
            stride = 32;
        }
        union { f16x8 v; unsigned u[4]; } t;
        t.u[0] = pkh(src[0 * stride], src[1 * stride]);
        t.u[1] = pkh(src[2 * stride], src[3 * stride]);
        t.u[2] = pkh(src[4 * stride], src[5 * stride]);
        t.u[3] = pkh(src[6 * stride], src[7 * stride]);
        *(f16x8*)(ws + F * 16) = t.v;
    }
    if (tid < 128) {                       // b1 frags
        const int e = tid >> 4, mt = (tid >> 2) & 3, q = tid & 3;
        *(f32x4*)(ws + 65536 + tid * 16) =
            *(const f32x4*)(b1 + e * 64 + 32 * (mt >> 1) + 4 * (mt & 1) + 8 * q);
    } else if (tid < 192) {                // b2 frags
        const int i = tid - 128, e = i >> 3, mt2 = (i >> 2) & 1, q = i & 3;
        *(f32x4*)(ws + 67584 + i * 16) =
            *(const f32x4*)(b2 + e * 32 + 4 * mt2 + 8 * q);
    } else if (tid < 224) {                // a3 frags (pre-packed f16)
        const int i = tid - 192, e = i >> 2, q = i & 3;
        const f32x4 lo = *(const f32x4*)(W3 + e * 32 + 8 * q);
        const f32x4 hi = *(const f32x4*)(W3 + e * 32 + 8 * q + 4);
        union { f16x8 v; unsigned u[4]; } a;
        a.u[0] = pkh(lo.x, lo.y); a.u[1] = pkh(lo.z, lo.w);
        a.u[2] = pkh(hi.x, hi.y); a.u[3] = pkh(hi.z, hi.w);
        *(f16x8*)(ws + 68608 + i * 16) = a.v;
    } else if (tid < 232) {                // b3
        const int i = tid - 224;
        *(float*)(ws + 69120 + i * 4) = b3[i];
    }
}

__global__ __launch_bounds__(512, 4)
void moe_fused(const float* __restrict__ x, const float* __restrict__ probs,
               const char* __restrict__ img, float* __restrict__ out) {
    __shared__ __attribute__((aligned(16))) char ldsraw[69632];
    const int tid = threadIdx.x;
    const int w = tid >> 6, lane = tid & 63, n = lane & 15, q = lane >> 4;

    // ---- prologue: linear coalesced copy of the prebuilt image.
    #pragma unroll
    for (int k = 0; k < 8; ++k) {
        const int off = tid * 16 + k * 8192;
        *(f32x4*)(ldsraw + off) = *(const f32x4*)(img + off);
    }
    if (tid < 226) {                        // tail 3616 B incl. b3
        const int off = 65536 + tid * 16;
        *(f32x4*)(ldsraw + off) = *(const f32x4*)(img + off);
    }

    // ---- per-wave x tiles: wave owns rows rb..rb+63 (four 16-row tiles).
    const int rb = blockIdx.x * 512 + w * 64;
    union { f16x8 v; unsigned u[4]; } xf[4];
    #pragma unroll
    for (int rt = 0; rt < 4; ++rt) {
        const float* xp = x + (size_t)(rb + rt * 16 + n) * 32 + q * 8;
        const f32x4 xa = *(const f32x4*)xp, xb = *(const f32x4*)(xp + 4);
        xf[rt].u[0] = pkh(xa.x, xa.y); xf[rt].u[1] = pkh(xa.z, xa.w);
        xf[rt].u[2] = pkh(xb.x, xb.y); xf[rt].u[3] = pkh(xb.z, xb.w);
    }

    __syncthreads();

    const short* wl = (const short*)ldsraw + (n * 8 + q * 128);
    const char* bb1 = ldsraw + 65536 + q * 16;   // + e*256 + mt*64
    const char* bb2 = ldsraw + 67584 + q * 16;   // + e*128 + mt2*64
    const char* ba3 = ldsraw + 68608 + q * 16;   // + e*64
    const float* b3l = (const float*)(ldsraw + 69120);
    const float* pba = probs + (size_t)(rb + n) * 8;   // + e + rt*128
    float r[4] = {0.f, 0.f, 0.f, 0.f};

    #pragma unroll 1
    for (int e = 0; e < 8; ++e) {
        const short* we = wl + e * 2048;

        // Layer 1: 4 mt-tiles x 4 row-tiles. pack+relu into P[rt][kb2]
        // (element j <-> h = 32kb2 + 8q + j).
        union { f16x8 v; unsigned u[4]; } P[4][2];
        #pragma unroll
        for (int mt = 0; mt < 4; ++mt) {
            const f16x8 w1f = *(const f16x8*)(we + mt * 512);
            const f32x4 bf = *(const f32x4*)(bb1 + e * 256 + mt * 64);
            f32x4 c[4];
            #pragma unroll
            for (int rt = 0; rt < 4; ++rt) c[rt] = MFMA32(w1f, xf[rt].v, bf);
            #pragma unroll
            for (int rt = 0; rt < 4; ++rt) {
                P[rt][mt >> 1].u[(mt & 1) * 2 + 0] = relu2(pkh(c[rt].x, c[rt].y));
                P[rt][mt >> 1].u[(mt & 1) * 2 + 1] = relu2(pkh(c[rt].z, c[rt].w));
            }
        }

        // Layer 2: 2 mt2 x 2 kb2 x 4 row-tiles. pack+relu into PC[rt]
        // (element j <-> h2 = 8q+j).
        union { f16x8 v; unsigned u[4]; } PC[4];
        #pragma unroll
        for (int mt2 = 0; mt2 < 2; ++mt2) {
            const f32x4 bf = *(const f32x4*)(bb2 + e * 128 + mt2 * 64);
            f32x4 c[4];
            #pragma unroll
            for (int rt = 0; rt < 4; ++rt) c[rt] = bf;
            #pragma unroll
            for (int kb2 = 0; kb2 < 2; ++kb2) {
                const f16x8 w2f =
                    *(const f16x8*)(we + 16384 + mt2 * 512 + kb2 * 1024);
                #pragma unroll
                for (int rt = 0; rt < 4; ++rt)
                    c[rt] = MFMA32(w2f, P[rt][kb2].v, c[rt]);
            }
            #pragma unroll
            for (int rt = 0; rt < 4; ++rt) {
                PC[rt].u[mt2 * 2 + 0] = relu2(pkh(c[rt].x, c[rt].y));
                PC[rt].u[mt2 * 2 + 1] = relu2(pkh(c[rt].z, c[rt].w));
            }
        }

        // Layer 3: pre-packed w3 frag (LDS); b3 seeded into C operand.
        const f16x8 a3v = *(const f16x8*)(ba3 + e * 64);
        const float bb = b3l[e];   // wave-uniform
        const f32x4 cb = {bb, bb, bb, bb};
        #pragma unroll
        for (int rt = 0; rt < 4; ++rt) {
            const f32x4 s = MFMA32(a3v, PC[rt].v, cb);
            r[rt] = fmaf(sigf(s.x), pba[e + rt * 128], r[rt]);
        }
    }

    if (q == 0) {
        #pragma unroll
        for (int rt = 0; rt < 4; ++rt) out[rb + rt * 16 + n] = r[rt];
    }
}

extern "C" void kernel_launch(void* const* d_in, const int* in_sizes, int n_in,
                              void* d_out, int out_size, void* d_ws, size_t ws_size,
                              hipStream_t stream) {
    const float* x     = (const float*)d_in[0];
    const float* probs = (const float*)d_in[1];
    const float* W1    = (const float*)d_in[2];
    const float* b1    = (const float*)d_in[3];
    const float* W2    = (const float*)d_in[4];
    const float* b2    = (const float*)d_in[5];
    const float* W3    = (const float*)d_in[6];
    const float* b3    = (const float*)d_in[7];

    hipLaunchKernelGGL(build_image, dim3(1), dim3(1024), 0, stream,
                       W1, b1, W2, b2, W3, b3, (char*)d_ws);
    const int nrows = in_sizes[0] / 32;          // 524288
    hipLaunchKernelGGL(moe_fused, dim3(nrows / 512), dim3(512), 0, stream,
                       x, probs, (const char*)d_ws, (float*)d_out);
}